// Round 9
// baseline (764.792 us; speedup 1.0000x reference)
//
#include <hip/hip_runtime.h>
#include <hip/hip_fp16.h>

// Problem constants
#define NN 100000
#define NE 1600000
#define DIN 32
#define DE 16
#define HC 64
#define NL 4
#define MHC 128
#define OUTC 10
#define NG 128

typedef _Float16 half4_t __attribute__((ext_vector_type(4)));
typedef float f32x4 __attribute__((ext_vector_type(4)));

// ---- CSR build ----
__global__ __launch_bounds__(256) void k_deg(const int* __restrict__ dst, int* __restrict__ deg) {
  int e = blockIdx.x * 256 + threadIdx.x;
  if (e < NE) atomicAdd(&deg[dst[e]], 1);
}

__global__ __launch_bounds__(1024) void k_scan1(const int* __restrict__ deg, int* __restrict__ offs, int* __restrict__ bsum) {
  __shared__ int s[1024];
  int t = threadIdx.x;
  int i = blockIdx.x * 1024 + t;
  int v = (i < NN) ? deg[i] : 0;
  s[t] = v; __syncthreads();
  for (int d = 1; d < 1024; d <<= 1) {
    int x = 0;
    if (t >= d) x = s[t - d];
    __syncthreads();
    if (t >= d) s[t] += x;
    __syncthreads();
  }
  if (i < NN) offs[i] = s[t] - v;
  if (t == 1023) bsum[blockIdx.x] = s[t];
}

__global__ __launch_bounds__(128) void k_scan2(int* __restrict__ bsum, int nb) {
  __shared__ int s[128];
  int t = threadIdx.x;
  int v = (t < nb) ? bsum[t] : 0;
  s[t] = v; __syncthreads();
  for (int d = 1; d < 128; d <<= 1) {
    int x = 0;
    if (t >= d) x = s[t - d];
    __syncthreads();
    if (t >= d) s[t] += x;
    __syncthreads();
  }
  if (t < nb) bsum[t] = s[t] - v;
}

// also builds odeg = (start, deg) int2
__global__ __launch_bounds__(256) void k_scan3(int* __restrict__ offs, const int* __restrict__ bsum,
                                               const int* __restrict__ deg,
                                               int* __restrict__ cur, int2* __restrict__ odeg) {
  int i = blockIdx.x * 256 + threadIdx.x;
  if (i < NN) {
    int o = offs[i] + bsum[i >> 10];
    offs[i] = o;
    cur[i] = o;
    odeg[i] = make_int2(o, deg[i]);
  }
}

// ---- fused fill + cast: one pass over edges (coalesced reads of src/dst/eattr),
//      scatter-write csrc (4B) + e16 (32B, single 64B line) at CSR position. ----
__global__ __launch_bounds__(256) void k_fillcast(const int* __restrict__ src, const int* __restrict__ dst,
                                                  int* __restrict__ cur,
                                                  const float4* __restrict__ eattr4,
                                                  int* __restrict__ csrc, uint4* __restrict__ e16) {
  int e = blockIdx.x * 256 + threadIdx.x;
  if (e >= NE) return;
  int d = dst[e];
  float4 a0 = eattr4[(size_t)e * 4 + 0];
  float4 a1 = eattr4[(size_t)e * 4 + 1];
  float4 a2 = eattr4[(size_t)e * 4 + 2];
  float4 a3 = eattr4[(size_t)e * 4 + 3];
  int s = src[e];
  int pos = atomicAdd(&cur[d], 1);
  __half2 h0 = __floats2half2_rn(a0.x, a0.y), h1 = __floats2half2_rn(a0.z, a0.w);
  __half2 h2 = __floats2half2_rn(a1.x, a1.y), h3 = __floats2half2_rn(a1.z, a1.w);
  __half2 h4 = __floats2half2_rn(a2.x, a2.y), h5 = __floats2half2_rn(a2.z, a2.w);
  __half2 h6 = __floats2half2_rn(a3.x, a3.y), h7 = __floats2half2_rn(a3.z, a3.w);
  uint4 o0 = make_uint4(*(unsigned*)&h0, *(unsigned*)&h1, *(unsigned*)&h2, *(unsigned*)&h3);
  uint4 o1 = make_uint4(*(unsigned*)&h4, *(unsigned*)&h5, *(unsigned*)&h6, *(unsigned*)&h7);
  csrc[pos] = s;
  e16[(size_t)pos * 2 + 0] = o0;
  e16[(size_t)pos * 2 + 1] = o1;
}

// ---- edge weights -> MFMA B-fragment layout [4 layers][4 grp][64 lane][2 dw]
//      + padded biases [4][64] ----
__global__ __launch_bounds__(256) void k_wprep(const float* __restrict__ l0ew, const float* __restrict__ l0eb,
                                               const float* __restrict__ ew, const float* __restrict__ eb,
                                               unsigned* __restrict__ ewmf, float* __restrict__ ebp) {
  int i = blockIdx.x * 256 + threadIdx.x;
  if (i < 2048) {
    int j = i & 1;           // dword within lane fragment
    int l = (i >> 1) & 63;   // lane
    int g = (i >> 7) & 3;    // channel group
    int L = i >> 9;          // layer
    int ch = 16 * g + (l & 15);
    int k0 = 4 * (l >> 4) + 2 * j;
    float a, b;
    if (L == 0) {
      a = (ch < 32) ? l0ew[ch * 16 + k0] : 0.f;
      b = (ch < 32) ? l0ew[ch * 16 + k0 + 1] : 0.f;
    } else {
      a = ew[(size_t)(L - 1) * 1024 + ch * 16 + k0];
      b = ew[(size_t)(L - 1) * 1024 + ch * 16 + k0 + 1];
    }
    __half2 h = __floats2half2_rn(a, b);
    ewmf[i] = *(unsigned*)&h;
  }
  if (i < 256) {
    int L = i >> 6, c = i & 63;
    ebp[i] = (L == 0) ? ((c < 32) ? l0eb[c] : 0.f) : eb[(size_t)(L - 1) * 64 + c];
  }
}

// ---- node-MLP weights -> MFMA B-fragments, f16.
//      wB[L][mat][kb][cg][lane][j]: value pair = W[c][k0], W[c][k0+1]
//      with c = cg*16+(lane&15), k0 = kb*16 + 4*(lane>>4) + 2*j.
//      mat0 = w1 (layer0: [64][32], k>=32 zero), mat1 = w2 ([64][64]). ----
__global__ __launch_bounds__(256) void k_wmlp(const float* __restrict__ l0w1, const float* __restrict__ w1,
                                              const float* __restrict__ l0w2, const float* __restrict__ w2,
                                              unsigned* __restrict__ wB) {
  int id = blockIdx.x * 256 + threadIdx.x;
  if (id >= 16384) return;
  int j = id & 1;
  int l = (id >> 1) & 63;
  int cg = (id >> 7) & 3;
  int kb = (id >> 9) & 3;
  int mat = (id >> 11) & 1;
  int L = (id >> 12) & 3;
  int k0 = kb * 16 + 4 * (l >> 4) + 2 * j;
  int c = cg * 16 + (l & 15);
  float a, b;
  if (mat == 0) {
    if (L == 0) {
      a = (k0 < 32) ? l0w1[c * 32 + k0] : 0.f;
      b = (k0 + 1 < 32) ? l0w1[c * 32 + k0 + 1] : 0.f;
    } else {
      a = w1[(size_t)(L - 1) * 4096 + c * 64 + k0];
      b = w1[(size_t)(L - 1) * 4096 + c * 64 + k0 + 1];
    }
  } else {
    if (L == 0) {
      a = l0w2[c * 64 + k0];
      b = l0w2[c * 64 + k0 + 1];
    } else {
      a = w2[(size_t)(L - 1) * 4096 + c * 64 + k0];
      b = w2[(size_t)(L - 1) * 4096 + c * 64 + k0 + 1];
    }
  }
  __half2 h = __floats2half2_rn(a, b);
  wB[id] = *(unsigned*)&h;
}

// ---- graph boundaries (batch sorted) ----
__global__ __launch_bounds__(256) void k_gstart(const int* __restrict__ batch, int* __restrict__ gstart) {
  int i = blockIdx.x * 256 + threadIdx.x;
  if (i >= NN) return;
  int b = batch[i];
  int bp = (i == 0) ? -1 : batch[i - 1];
  for (int g = bp + 1; g <= b; g++) gstart[g] = i;
  if (i == NN - 1)
    for (int g = b + 1; g <= NG; g++) gstart[g] = NN;
}

// ---- x -> f16 channel-interleaved gather layout xg16[row][(c&15)*4 + (c>>4)],
//      ch>=32 zero (layer-0 padding). ----
__global__ __launch_bounds__(256) void k_xpad16(const float* __restrict__ x, _Float16* __restrict__ xg16) {
  int i = blockIdx.x * 256 + threadIdx.x;   // over NN*64
  if (i >= NN * 64) return;
  int row = i >> 6, c = i & 63;
  float v = (c < 32) ? x[(size_t)row * 32 + c] : 0.f;
  xg16[(size_t)row * 64 + (c & 15) * 4 + (c >> 4)] = (_Float16)v;
}

// ---- BN+relu applied once per layer: h2 (f32) -> xg16 (f16, interleaved). ----
__global__ __launch_bounds__(256) void k_bnapply(const float* __restrict__ h2,
                                                 const float* __restrict__ sc, const float* __restrict__ sh,
                                                 _Float16* __restrict__ xg16) {
  int i = blockIdx.x * 256 + threadIdx.x;   // over NN*64
  if (i >= NN * 64) return;
  int row = i >> 6, c = i & 63;
  float v = fmaxf(fmaf(h2[i], sc[c], sh[c]), 0.f);
  xg16[(size_t)row * 64 + (c & 15) * 4 + (c >> 4)] = (_Float16)v;
}

// ---- fused layer v2: edge aggregation -> f16 LDS tile -> node MLP (MFMA).
//      R8 lessons applied: (1) hl stored f16 in A-fragment layout — stage A
//      converted to f16 anyway, so this is value-identical, halves the tile
//      (LDS 26.6->18.4 KB => more blocks/CU), and removes 64 cvts/thread.
//      (2) phase-1 node-ahead prefetch: wave's 16 odeg entries preloaded via
//      lanes 0..15 + shfl; node t+1's first e16/csrc chunk issued before
//      node t's gather/accum, hiding HBM latency (mean degree = 16 => most
//      nodes are exactly one chunk). ----
__global__ __launch_bounds__(256) void k_layer(
    const int* __restrict__ csrc, const int2* __restrict__ odeg,
    const _Float16* __restrict__ xg16,
    const unsigned* __restrict__ e16,
    const unsigned* __restrict__ ewmf, const float* __restrict__ ebf,
    const unsigned* __restrict__ wBL,   // [mat][kb][cg][lane][2] dwords
    const float* __restrict__ b1f, const float* __restrict__ b2v,
    float* __restrict__ h2, float* __restrict__ bnsq)
{
  __shared__ _Float16 hl[64 * 72];   // aggregated node features (f16), stride 72
  __shared__ _Float16 ml[64 * 72];   // mid activations (f16), stride 72
  int tid = threadIdx.x;
  int cg = __builtin_amdgcn_readfirstlane(tid >> 6);   // wave id = col group
  int l = tid & 63;
  int m = l & 15;    // A row / col-in-group
  int q = l >> 4;    // lane quarter
  int rbase = blockIdx.x * 64;
  int col = cg * 16 + m;

  // edge-linear B fragments + bias
  half4_t bf[4];
  #pragma unroll
  for (int g = 0; g < 4; g++) {
    uint2 wv = *(const uint2*)(ewmf + (size_t)(g * 64 + l) * 2);
    bf[g] = __builtin_bit_cast(half4_t, wv);
  }
  float bb[4];
  #pragma unroll
  for (int g = 0; g < 4; g++) bb[g] = ebf[16 * g + m];
  // node-MLP B fragments + biases (issued early; live through phase 1)
  uint2 w1f[4], w2f[4];
  #pragma unroll
  for (int kb = 0; kb < 4; kb++) {
    w1f[kb] = *(const uint2*)(wBL + (size_t)(((0 * 4 + kb) * 4 + cg) * 64 + l) * 2);
    w2f[kb] = *(const uint2*)(wBL + (size_t)(((1 * 4 + kb) * 4 + cg) * 64 + l) * 2);
  }
  float b1c = b1f[col], b2c = b2v[col];

  // preload odeg for this wave's 16 nodes (lanes 0..15), distribute via shfl
  int2 odl = make_int2(0, 0);
  if (l < 16) {
    int nn_ = rbase + cg * 16 + l;
    if (nn_ < NN) odl = odeg[nn_];
  }

  // ---- phase 1: edge aggregation, 16 nodes per wave, node-ahead prefetch ----
  int cur_start = __shfl(odl.x, 0);
  int cur_n = __shfl(odl.y, 0);
  uint2 av_p = *(const uint2*)(e16 + (size_t)(cur_start + m) * 8 + q * 2);
  int sid_p = csrc[cur_start + m];
  for (int t = 0; t < 16; t++) {
    int start = cur_start, n = cur_n;
    uint2 av0 = av_p; int sid0 = sid_p;
    if (t < 15) {
      cur_start = __shfl(odl.x, t + 1);
      cur_n = __shfl(odl.y, t + 1);
      av_p = *(const uint2*)(e16 + (size_t)(cur_start + m) * 8 + q * 2);
      sid_p = csrc[cur_start + m];
    }
    int node = rbase + cg * 16 + t;
    float hv = 0.f;
    if (node < NN) {
      float acc[4] = {0.f, 0.f, 0.f, 0.f};
      for (int base = 0; base < n; base += 16) {
        int cn = n - base;
        uint2 av; int sidx;
        if (base == 0) { av = av0; sidx = sid0; }
        else {
          int p = start + base;
          av = *(const uint2*)(e16 + (size_t)(p + m) * 8 + q * 2);
          sidx = csrc[p + m];
        }
        half4_t af = __builtin_bit_cast(half4_t, av);
        f32x4 d0, d1, d2, d3;
        {
          f32x4 ci;
          ci[0] = bb[0]; ci[1] = bb[0]; ci[2] = bb[0]; ci[3] = bb[0];
          d0 = __builtin_amdgcn_mfma_f32_16x16x16f16(af, bf[0], ci, 0, 0, 0);
          ci[0] = bb[1]; ci[1] = bb[1]; ci[2] = bb[1]; ci[3] = bb[1];
          d1 = __builtin_amdgcn_mfma_f32_16x16x16f16(af, bf[1], ci, 0, 0, 0);
          ci[0] = bb[2]; ci[1] = bb[2]; ci[2] = bb[2]; ci[3] = bb[2];
          d2 = __builtin_amdgcn_mfma_f32_16x16x16f16(af, bf[2], ci, 0, 0, 0);
          ci[0] = bb[3]; ci[1] = bb[3]; ci[2] = bb[3]; ci[3] = bb[3];
          d3 = __builtin_amdgcn_mfma_f32_16x16x16f16(af, bf[3], ci, 0, 0, 0);
        }
        #pragma unroll
        for (int r = 0; r < 4; r++) {
          int s = __shfl(sidx, 4 * q + r);
          bool valid = (4 * q + r) < cn;
          uint2 xv = *(const uint2*)(xg16 + (size_t)s * 64 + m * 4);
          half4_t hx = __builtin_bit_cast(half4_t, xv);
          #pragma unroll
          for (int g = 0; g < 4; g++) {
            float xs = (float)hx[g];
            float el = (r == 0) ? ((g == 0) ? d0[0] : (g == 1) ? d1[0] : (g == 2) ? d2[0] : d3[0])
                     : (r == 1) ? ((g == 0) ? d0[1] : (g == 1) ? d1[1] : (g == 2) ? d2[1] : d3[1])
                     : (r == 2) ? ((g == 0) ? d0[2] : (g == 1) ? d1[2] : (g == 2) ? d2[2] : d3[2])
                     :            ((g == 0) ? d0[3] : (g == 1) ? d1[3] : (g == 2) ? d2[3] : d3[3]);
            float v = fmaxf(xs + el, 0.f);
            acc[g] += valid ? v : 0.f;
          }
        }
      }
      #pragma unroll
      for (int g = 0; g < 4; g++) {
        acc[g] += __shfl_xor(acc[g], 16);
        acc[g] += __shfl_xor(acc[g], 32);
      }
      float xself = (float)xg16[(size_t)node * 64 + (l & 15) * 4 + (l >> 4)];
      float sum = (q == 0) ? acc[0] : (q == 1) ? acc[1] : (q == 2) ? acc[2] : acc[3];
      hv = xself + sum;
    }
    hl[(cg * 16 + t) * 72 + l] = (_Float16)hv;   // lane l = channel l (k index)
  }
  __syncthreads();

  // ---- phase 2 stage A: mid = relu(hl @ w1^T + b1) -> ml (f16) ----
  #pragma unroll
  for (int rg = 0; rg < 4; rg++) {
    f32x4 acc; acc[0] = b1c; acc[1] = b1c; acc[2] = b1c; acc[3] = b1c;
    #pragma unroll
    for (int kb = 0; kb < 4; kb++) {
      half4_t a = *(const half4_t*)(hl + (rg * 16 + m) * 72 + kb * 16 + 4 * q);
      acc = __builtin_amdgcn_mfma_f32_16x16x16f16(a, __builtin_bit_cast(half4_t, w1f[kb]), acc, 0, 0, 0);
    }
    #pragma unroll
    for (int i = 0; i < 4; i++)
      ml[(rg * 16 + q * 4 + i) * 72 + col] = (_Float16)fmaxf(acc[i], 0.f);
  }
  __syncthreads();

  // ---- phase 2 stage B: out = relu(mid @ w2^T + b2); h2 store + BN stats ----
  float sacc = 0.f, qacc = 0.f;
  #pragma unroll
  for (int rg = 0; rg < 4; rg++) {
    f32x4 acc; acc[0] = b2c; acc[1] = b2c; acc[2] = b2c; acc[3] = b2c;
    #pragma unroll
    for (int kb = 0; kb < 4; kb++) {
      half4_t a = *(const half4_t*)(ml + (rg * 16 + m) * 72 + kb * 16 + 4 * q);
      acc = __builtin_amdgcn_mfma_f32_16x16x16f16(a, __builtin_bit_cast(half4_t, w2f[kb]), acc, 0, 0, 0);
    }
    #pragma unroll
    for (int i = 0; i < 4; i++) {
      int row = rbase + rg * 16 + q * 4 + i;
      bool rok = row < NN;
      float v = rok ? fmaxf(acc[i], 0.f) : 0.f;
      if (rok) h2[(size_t)row * 64 + col] = v;
      sacc += v; qacc += v * v;
    }
  }
  sacc += __shfl_xor(sacc, 16); sacc += __shfl_xor(sacc, 32);
  qacc += __shfl_xor(qacc, 16); qacc += __shfl_xor(qacc, 32);
  int cp = (blockIdx.x & 31) * 128;
  if (q == 0) {
    atomicAdd(&bnsq[cp + col], sacc);
    atomicAdd(&bnsq[cp + 64 + col], qacc);
  }
}

__global__ __launch_bounds__(64) void k_bnfin(const float* __restrict__ bnsq,
                                              const float* __restrict__ gamma, const float* __restrict__ beta,
                                              int layer, float* __restrict__ scs, float* __restrict__ shs) {
  int c = threadIdx.x;
  if (c >= 64) return;
  const float* sl = bnsq + (size_t)layer * 4096;
  float s = 0.f, q = 0.f;
  for (int cp = 0; cp < 32; cp++) { s += sl[cp * 128 + c]; q += sl[cp * 128 + 64 + c]; }
  float mu = s * (1.0f / NN);
  float var = q * (1.0f / NN) - mu * mu;
  float r = rsqrtf(var + 1e-5f);
  float g = gamma[layer * 64 + c] * r;
  scs[layer * 64 + c] = g;
  shs[layer * 64 + c] = beta[layer * 64 + c] - mu * g;
}

// ---- pool: BN+relu on the fly; batch sorted -> contiguous ranges ----
__global__ __launch_bounds__(256) void k_pool2(const float* __restrict__ h2, const float* __restrict__ sc,
                                               const float* __restrict__ sh, const int* __restrict__ gstart,
                                               float* __restrict__ pooled) {
  int g = blockIdx.x >> 2, sub = blockIdx.x & 3;
  int s = gstart[g], e = gstart[g + 1];
  int c = threadIdx.x & 63, rg = threadIdx.x >> 6;
  float scv = sc[c], shv = sh[c];
  float acc = 0.f;
  for (int r = s + sub * 4 + rg; r < e; r += 16)
    acc += fmaxf(fmaf(h2[(size_t)r * 64 + c], scv, shv), 0.f);
  __shared__ float ls[256];
  ls[threadIdx.x] = acc;
  __syncthreads();
  if (rg == 0) {
    float v = ls[c] + ls[64 + c] + ls[128 + c] + ls[192 + c];
    atomicAdd(&pooled[g * 64 + c], v);
  }
}

__global__ __launch_bounds__(128) void k_head(const float* __restrict__ pooled, const int* __restrict__ gstart,
                                              const float* __restrict__ hw1, const float* __restrict__ hb1,
                                              const float* __restrict__ hw2, const float* __restrict__ hb2,
                                              float* __restrict__ out) {
  __shared__ float p[64];
  __shared__ float z[128];
  int g = blockIdx.x, t = threadIdx.x;
  if (t < 64) {
    int cn = gstart[g + 1] - gstart[g];
    float inv = 1.0f / (float)(cn > 0 ? cn : 1);
    p[t] = pooled[g * 64 + t] * inv;
  }
  __syncthreads();
  float a = hb1[t];
  #pragma unroll
  for (int k = 0; k < 64; k++) a = fmaf(hw1[t * 64 + k], p[k], a);
  z[t] = fmaxf(a, 0.f);
  __syncthreads();
  if (t < OUTC) {
    float b = hb2[t];
    #pragma unroll
    for (int k = 0; k < 128; k++) b = fmaf(hw2[t * 128 + k], z[k], b);
    out[g * OUTC + t] = b;
  }
}

extern "C" void kernel_launch(void* const* d_in, const int* in_sizes, int n_in,
                              void* d_out, int out_size, void* d_ws, size_t ws_size,
                              hipStream_t stream) {
  const float* x_f   = (const float*)d_in[0];
  const int*   ei    = (const int*)d_in[1];
  const float* eattr = (const float*)d_in[2];
  const int*   batch = (const int*)d_in[3];
  const float* l0_ew = (const float*)d_in[4];
  const float* l0_eb = (const float*)d_in[5];
  const float* l0_w1 = (const float*)d_in[6];
  const float* l0_b1 = (const float*)d_in[7];
  const float* l0_w2 = (const float*)d_in[8];
  const float* l0_b2 = (const float*)d_in[9];
  const float* ew    = (const float*)d_in[10];
  const float* eb    = (const float*)d_in[11];
  const float* w1    = (const float*)d_in[12];
  const float* b1    = (const float*)d_in[13];
  const float* w2    = (const float*)d_in[14];
  const float* b2    = (const float*)d_in[15];
  const float* bng   = (const float*)d_in[16];
  const float* bnb   = (const float*)d_in[17];
  const float* hw1   = (const float*)d_in[18];
  const float* hb1   = (const float*)d_in[19];
  const float* hw2   = (const float*)d_in[20];
  const float* hb2   = (const float*)d_in[21];
  const int* esrc = ei;
  const int* edst = ei + NE;

  char* wsb = (char*)d_ws;
  size_t off = 0;
  auto A = [&](size_t bytes) -> void* {
    void* p = wsb + off;
    off = (off + bytes + 255) & ~(size_t)255;
    return p;
  };
  int*   csrc = (int*)A((size_t)(NE + 16) * 4);
  int*   offs = (int*)A((size_t)NN * 4);
  int*   deg  = (int*)A((size_t)NN * 4);
  int*   cur  = (int*)A((size_t)NN * 4);
  int2*  odeg = (int2*)A((size_t)NN * 8);
  int*   bsum = (int*)A(128 * 4);
  int*   gst  = (int*)A((NG + 1) * 4);
  _Float16* xg16 = (_Float16*)A((size_t)NN * 64 * 2);  // f16 interleaved gather operand
  float* h2   = (float*)A((size_t)NN * 64 * 4);
  float* bnsq = (float*)A(4 * 32 * 128 * 4);   // [layer][copy0..31][sum64|sq64]
  float* scs  = (float*)A(4 * 64 * 4);
  float* shs  = (float*)A(4 * 64 * 4);
  float* pooled = (float*)A((size_t)NG * 64 * 4);
  unsigned* wB   = (unsigned*)A(16384 * 4);  // MFMA B-frag node-MLP weights, 4 layers x 2 mats
  unsigned* ewmf = (unsigned*)A(2048 * 4);   // MFMA-layout f16 edge weights, 4 layers
  float* ebp  = (float*)A(256 * 4);          // padded edge biases, 4 layers
  unsigned* e16 = (unsigned*)A(((size_t)NE + 16) * 32);  // f16 eattr, CSR order, 8 dwords/edge

  hipMemsetAsync(deg, 0, (size_t)NN * 4, stream);
  hipMemsetAsync(bnsq, 0, 4 * 32 * 128 * 4, stream);
  hipMemsetAsync(pooled, 0, (size_t)NG * 64 * 4, stream);
  hipMemsetAsync(csrc + NE, 0, 16 * 4, stream);            // pad: safe src idx for tail chunks
  hipMemsetAsync((char*)e16 + (size_t)NE * 32, 0, 16 * 32, stream);  // pad: clean A-frag tail

  k_wmlp<<<64, 256, 0, stream>>>(l0_w1, w1, l0_w2, w2, wB);
  k_wprep<<<8, 256, 0, stream>>>(l0_ew, l0_eb, ew, eb, ewmf, ebp);
  k_xpad16<<<(NN * 64 + 255) / 256, 256, 0, stream>>>(x_f, xg16);
  k_gstart<<<(NN + 255) / 256, 256, 0, stream>>>(batch, gst);

  k_deg<<<(NE + 255) / 256, 256, 0, stream>>>(edst, deg);
  k_scan1<<<98, 1024, 0, stream>>>(deg, offs, bsum);
  k_scan2<<<1, 128, 0, stream>>>(bsum, 98);
  k_scan3<<<(NN + 255) / 256, 256, 0, stream>>>(offs, bsum, deg, cur, odeg);
  k_fillcast<<<(NE + 255) / 256, 256, 0, stream>>>(esrc, edst, cur, (const float4*)eattr,
                                                   csrc, (uint4*)e16);

  const int rowBlocks = (NN + 63) / 64;
  const int elemBlocks = (NN * 64 + 255) / 256;

  // ---- layer 0 (padded to C=64) ----
  k_layer<<<rowBlocks, 256, 0, stream>>>(csrc, odeg, xg16, e16, ewmf, ebp,
                                         wB, l0_b1, l0_b2, h2, bnsq + 0);
  k_bnfin<<<1, 64, 0, stream>>>(bnsq, bng, bnb, 0, scs, shs);

  // ---- layers 1..3: pre-apply BN(prev)+relu -> f16 gather operand ----
  for (int i = 0; i < 3; i++) {
    k_bnapply<<<elemBlocks, 256, 0, stream>>>(h2, scs + i * 64, shs + i * 64, xg16);
    k_layer<<<rowBlocks, 256, 0, stream>>>(csrc, odeg, xg16,
                                           e16, ewmf + (size_t)(i + 1) * 512, ebp + (i + 1) * 64,
                                           wB + (size_t)(i + 1) * 4096, b1 + (size_t)i * 64,
                                           b2 + (size_t)i * 64, h2, bnsq + (size_t)(i + 1) * 4096);
    k_bnfin<<<1, 64, 0, stream>>>(bnsq, bng, bnb, i + 1, scs, shs);
  }

  // ---- pool (applies BN layer 3) + head ----
  k_pool2<<<NG * 4, 256, 0, stream>>>(h2, scs + 3 * 64, shs + 3 * 64, gst, pooled);
  k_head<<<NG, 128, 0, stream>>>(pooled, gst, hw1, hb1, hw2, hb2, (float*)d_out);
}